// Round 1
// baseline (2630.685 us; speedup 1.0000x reference)
//
#include <hip/hip_runtime.h>

#define TT   512
#define IDIM 64
#define HDIM 256

typedef short  short8  __attribute__((ext_vector_type(8)));
typedef short  short4v __attribute__((ext_vector_type(4)));
typedef float  f32x4   __attribute__((ext_vector_type(4)));
typedef unsigned long long u64;

#define POIS 0xAAAAAAAAAAAAAAAAull

__device__ __forceinline__ short f2bf(float f) {
    unsigned u = __float_as_uint(f);
    u = u + 0x7FFFu + ((u >> 16) & 1u);   // round-to-nearest-even
    return (short)(u >> 16);
}
__device__ __forceinline__ float bf2f(short h) {
    return __uint_as_float(((unsigned)(unsigned short)h) << 16);
}
__device__ __forceinline__ float sigm(float x)  { return 1.0f / (1.0f + __expf(-x)); }
__device__ __forceinline__ float tanh_(float x) { return 2.0f / (1.0f + __expf(-2.0f * x)) - 1.0f; }

// ready iff word is neither our/harness poison (0xAA..) nor all-zero (covers a
// memset-0 workspace). Published words are ~bits of 4 bf16 h-values (|h|<=1):
//  == POIS would need 4x bf16 0x5555 (~1.2e13, impossible for |h|<=1)
//  == 0    would need 4x bf16 0xFFFF (NaN, impossible from finite math)
__device__ __forceinline__ bool rdy(u64 w) { return (w != POIS) & (w != 0ull); }

// 256 persistent workgroups = 16 batch-groups (16 rows) x 16 hidden-chunks (16 units).
// h exchange protocol (flagless): 4-phase (mod-4) global buffers; readers poll the
// NOT-encoded data words directly until != poison. Poison for region (s+2)&3 is
// installed at the TOP of iter s (after the end-of-iter barrier => all s-1 publishes
// observed => all s-2 readers of that region finished), ordered before this iter's
// publish by the funnel's s_waitcnt vmcnt(0) (ack hides under MFMA+cell).
__global__ __launch_bounds__(256, 1) void lstm_fused(
    const float* __restrict__ x,
    const float* __restrict__ Wih0, const float* __restrict__ Whh0,
    const float* __restrict__ bih0, const float* __restrict__ bhh0,
    const float* __restrict__ Wih1, const float* __restrict__ Whh1,
    const float* __restrict__ bih1, const float* __restrict__ bhh1,
    const float* __restrict__ Wfc,  const float* __restrict__ bfc,
    float* __restrict__ out, char* __restrict__ ws)
{
    short* h0buf = (short*)ws;                      // [4][16][16][256] bf16, ~encoded
    short* h1buf = h0buf + 4 * 16 * 16 * 256;       // [4][16][16][256] bf16, ~encoded

    const int blk   = blockIdx.x;
    const int grp   = ((blk & 7) << 1) | ((blk >> 3) & 1); // batch-group 0..15
    const int chunk = blk >> 4;                            // hidden-chunk 0..15
    const int tid   = threadIdx.x;
    const int lane  = tid & 63;
    const int wave  = tid >> 6;      // gate index: 0=i 1=f 2=g 3=o
    const int quad  = lane >> 4;
    const int nn    = lane & 15;     // W-row within 16-row tile (= hidden unit in chunk)

    __shared__ short A0[16][328];    // [m][ x(64) | h0(256) ] + pad
    __shared__ short A1[16][520];    // [m][ h0(256) | h1(256) ] + pad
    __shared__ float gbuf[2][4][16][16];
    __shared__ float red[16][16];
    __shared__ __align__(16) short hls[2][16][16];  // h staging for the publish funnel
    __shared__ float ldspad[5120];   // occupancy limiter: ~57 KB -> 1 wg/CU

    // zero A buffers (h0[-1] = 0, h1[-1] = 0 for the s==1 layer1 step)
    for (int i = tid; i < 16 * 328; i += 256) (&A0[0][0])[i] = 0;
    for (int i = tid; i < 16 * 520; i += 256) (&A1[0][0])[i] = 0;

    // ---- static weight fragments -> registers (B operand: W[n][k], n=lane&15, k=quad*8+j)
    const int wrow = wave * HDIM + chunk * 16 + nn;
    short8 w0f[10];   // layer0: kb 0..1 = Wih0 (K 0..63), kb 2..9 = Whh0 (K 64..319)
    short8 w1f[16];   // layer1: kb 0..7 = Wih1 (K 0..255), kb 8..15 = Whh1 (K 256..511)
#pragma unroll
    for (int kb = 0; kb < 10; ++kb)
#pragma unroll
        for (int j = 0; j < 8; ++j) {
            int k = kb * 32 + quad * 8 + j;
            float v = (k < 64) ? Wih0[wrow * IDIM + k] : Whh0[wrow * HDIM + (k - 64)];
            w0f[kb][j] = f2bf(v);
        }
#pragma unroll
    for (int kb = 0; kb < 16; ++kb)
#pragma unroll
        for (int j = 0; j < 8; ++j) {
            int k = kb * 32 + quad * 8 + j;
            float v = (k < 256) ? Wih1[wrow * HDIM + k] : Whh1[wrow * HDIM + (k - 256)];
            w1f[kb][j] = f2bf(v);
        }
    const float bias0 = bih0[wrow] + bhh0[wrow];
    const float bias1 = bih1[wrow] + bhh1[wrow];

    const int em = tid >> 4;   // elementwise batch row (0..15)
    const int ej = tid & 15;   // elementwise hidden unit within chunk
    float c0 = 0.0f, c1 = 0.0f;

    auto load_x = [&](int t) {
        const float4 v = *(const float4*)&x[((size_t)(grp * 16 + em) * TT + t) * IDIM + ej * 4];
        short4v sv;
        sv[0] = f2bf(v.x); sv[1] = f2bf(v.y); sv[2] = f2bf(v.z); sv[3] = f2bf(v.w);
        *(short4v*)&A0[em][ej * 4] = sv;
    };

    __syncthreads();
    load_x(0);
    __syncthreads();

    // super-step s: layer0 computes h0[s] (s<T); layer1 computes h1[s-1] (s>=1)
    for (int s = 0; s <= TT; ++s) {
        // ---- poison install for region (s+2)&3 (own chunk slice only).
        // Safe: past the end-of-prev-iter barrier, this block observed ALL s-1
        // publishes => every block finished its s-2 reads of region (s+2)&3.
        // Ordered before our s+2 data (and before observation of our s publish)
        // by the vmcnt(0) in this iter's funnel.
        if (tid < 64) {
            const int wm = tid >> 2, wp = tid & 3;
            const size_t pb = (((size_t)(((s + 2) & 3) * 16 + grp)) * 16 + wm) * 256
                              + chunk * 16 + wp * 4;
            __hip_atomic_store((u64*)&h0buf[pb], POIS, __ATOMIC_RELAXED, __HIP_MEMORY_SCOPE_AGENT);
            __hip_atomic_store((u64*)&h1buf[pb], POIS, __ATOMIC_RELAXED, __HIP_MEMORY_SCOPE_AGENT);
        }

        if (s < TT) {
            f32x4 accA = {0.f, 0.f, 0.f, 0.f}, accB = {0.f, 0.f, 0.f, 0.f};
#pragma unroll
            for (int kb = 0; kb < 10; kb += 2) {   // 2 chains: halve dep latency (1 wave/SIMD)
                short8 a0v = *(const short8*)&A0[nn][kb * 32 + quad * 8];
                short8 a1v = *(const short8*)&A0[nn][(kb + 1) * 32 + quad * 8];
                accA = __builtin_amdgcn_mfma_f32_16x16x32_bf16(a0v, w0f[kb],     accA, 0, 0, 0);
                accB = __builtin_amdgcn_mfma_f32_16x16x32_bf16(a1v, w0f[kb + 1], accB, 0, 0, 0);
            }
            const f32x4 acc = accA + accB;
#pragma unroll
            for (int r = 0; r < 4; ++r)
                gbuf[0][wave][quad * 4 + r][nn] = acc[r] + bias0;
        }
        if (s >= 1) {
            f32x4 accA = {0.f, 0.f, 0.f, 0.f}, accB = {0.f, 0.f, 0.f, 0.f};
#pragma unroll
            for (int kb = 0; kb < 16; kb += 2) {
                short8 a0v = *(const short8*)&A1[nn][kb * 32 + quad * 8];
                short8 a1v = *(const short8*)&A1[nn][(kb + 1) * 32 + quad * 8];
                accA = __builtin_amdgcn_mfma_f32_16x16x32_bf16(a0v, w1f[kb],     accA, 0, 0, 0);
                accB = __builtin_amdgcn_mfma_f32_16x16x32_bf16(a1v, w1f[kb + 1], accB, 0, 0, 0);
            }
            const f32x4 acc = accA + accB;
#pragma unroll
            for (int r = 0; r < 4; ++r)
                gbuf[1][wave][quad * 4 + r][nn] = acc[r] + bias1;
        }
        __syncthreads();

        // elementwise LSTM cell updates -> stage h in LDS (bf16)
        if (s < TT) {
            float gi = sigm (gbuf[0][0][em][ej]);
            float gf = sigm (gbuf[0][1][em][ej]);
            float gg = tanh_(gbuf[0][2][em][ej]);
            float go = sigm (gbuf[0][3][em][ej]);
            c0 = gf * c0 + gi * gg;
            hls[0][em][ej] = f2bf(go * tanh_(c0));
        }
        if (s >= 1) {
            float gi = sigm (gbuf[1][0][em][ej]);
            float gf = sigm (gbuf[1][1][em][ej]);
            float gg = tanh_(gbuf[1][2][em][ej]);
            float go = sigm (gbuf[1][3][em][ej]);
            c1 = gf * c1 + gi * gg;
            hls[1][em][ej] = f2bf(go * tanh_(c1));
        } else {
            hls[1][em][ej] = 0;
        }
        __syncthreads();   // hls complete

        // publish own h chunk, NOT-encoded. vmcnt(0) orders this iter's poison
        // (issued ~MFMA+cell earlier, ack hidden) before the data becomes visible.
        if (tid < 64) {
            const int wm = tid >> 2, wp = tid & 3;
            const u64 v0 = ~(*(const u64*)&hls[0][wm][wp * 4]);
            const u64 v1 = ~(*(const u64*)&hls[1][wm][wp * 4]);
            const size_t db = (((size_t)((s & 3) * 16 + grp)) * 16 + wm) * 256
                              + chunk * 16 + wp * 4;
            asm volatile("s_waitcnt vmcnt(0)" ::: "memory");
            __hip_atomic_store((u64*)&h0buf[db], v0, __ATOMIC_RELAXED, __HIP_MEMORY_SCOPE_AGENT);
            __hip_atomic_store((u64*)&h1buf[db], v1, __ATOMIC_RELAXED, __HIP_MEMORY_SCOPE_AGENT);
        }

        if (s + 1 < TT) load_x(s + 1);   // overlap x prefetch with the poll

        // ---- direct data poll + gather (the poll result IS the gathered data).
        // Thread (em,ej) owns words {ej+16i}, i=0..3 of its row: consecutive lanes
        // touch adjacent 8B in global AND in LDS (conflict-free ds_write_b64).
        {
            const bool g0 = (s < TT), g1 = (s >= 1);
            const size_t rb = (((size_t)((s & 3) * 16 + grp)) * 16 + em) * 256;
            const u64* p0 = (const u64*)&h0buf[rb];
            const u64* p1 = (const u64*)&h1buf[rb];
            u64 w0[4] = {POIS, POIS, POIS, POIS};
            u64 w1[4] = {POIS, POIS, POIS, POIS};
            if (g0) {
#pragma unroll
                for (int i = 0; i < 4; ++i)
                    w0[i] = __hip_atomic_load(p0 + ej + 16 * i,
                                              __ATOMIC_RELAXED, __HIP_MEMORY_SCOPE_AGENT);
            }
            if (g1) {
#pragma unroll
                for (int i = 0; i < 4; ++i)
                    w1[i] = __hip_atomic_load(p1 + ej + 16 * i,
                                              __ATOMIC_RELAXED, __HIP_MEMORY_SCOPE_AGENT);
            }
            for (;;) {
                bool done = true;
#pragma unroll
                for (int i = 0; i < 4; ++i) {
                    if (g0 && !rdy(w0[i])) {
                        done = false;
                        w0[i] = __hip_atomic_load(p0 + ej + 16 * i,
                                                  __ATOMIC_RELAXED, __HIP_MEMORY_SCOPE_AGENT);
                    }
                    if (g1 && !rdy(w1[i])) {
                        done = false;
                        w1[i] = __hip_atomic_load(p1 + ej + 16 * i,
                                                  __ATOMIC_RELAXED, __HIP_MEMORY_SCOPE_AGENT);
                    }
                }
                if (done) break;
            }
            if (g0) {
#pragma unroll
                for (int i = 0; i < 4; ++i) {
                    const u64 d = ~w0[i];
                    *(u64*)&A0[em][64 + (ej + 16 * i) * 4] = d;
                    *(u64*)&A1[em][     (ej + 16 * i) * 4] = d;
                }
            }
            if (g1) {
#pragma unroll
                for (int i = 0; i < 4; ++i)
                    *(u64*)&A1[em][256 + (ej + 16 * i) * 4] = ~w1[i];
            }
        }
        __syncthreads();
    }

    // FC epilogue: A1[:,256..511] holds h1[T-1] (bf16)
    {
        float part = 0.f;
#pragma unroll
        for (int kk = 0; kk < 16; ++kk) {
            int k = ej * 16 + kk;
            part += bf2f(A1[em][256 + k]) * Wfc[k];
        }
        red[em][ej] = part;
    }
    __syncthreads();
    if (chunk == 0 && tid < 16) {
        float sum = bfc[0];
#pragma unroll
        for (int c = 0; c < 16; ++c) sum += red[tid][c];
        out[grp * 16 + tid] = sum;
    }

    // keep ldspad allocated (occupancy cap); never true at runtime
    if (gridDim.x > 100000) { ldspad[tid] = bias0; out[0] = ldspad[255 - tid]; }
}

extern "C" void kernel_launch(void* const* d_in, const int* in_sizes, int n_in,
                              void* d_out, int out_size, void* d_ws, size_t ws_size,
                              hipStream_t stream) {
    (void)in_sizes; (void)n_in; (void)out_size; (void)ws_size;
    const float* x    = (const float*)d_in[0];
    const float* Wih0 = (const float*)d_in[1];
    const float* Whh0 = (const float*)d_in[2];
    const float* bih0 = (const float*)d_in[3];
    const float* bhh0 = (const float*)d_in[4];
    const float* Wih1 = (const float*)d_in[5];
    const float* Whh1 = (const float*)d_in[6];
    const float* bih1 = (const float*)d_in[7];
    const float* bhh1 = (const float*)d_in[8];
    const float* Wfc  = (const float*)d_in[9];
    const float* bfc  = (const float*)d_in[10];

    lstm_fused<<<256, 256, 0, stream>>>(x, Wih0, Whh0, bih0, bhh0,
                                        Wih1, Whh1, bih1, bhh1, Wfc, bfc,
                                        (float*)d_out, (char*)d_ws);
}

// Round 5
// 1810.360 us; speedup vs baseline: 1.4531x; 1.4531x over previous
//
#include <hip/hip_runtime.h>

#define TT   512
#define IDIM 64
#define HDIM 256

typedef short  short8  __attribute__((ext_vector_type(8)));
typedef short  short4v __attribute__((ext_vector_type(4)));
typedef float  f32x4   __attribute__((ext_vector_type(4)));
typedef unsigned long long u64;

__device__ __forceinline__ short f2bf(float f) {
    unsigned u = __float_as_uint(f);
    u = u + 0x7FFFu + ((u >> 16) & 1u);   // round-to-nearest-even
    return (short)(u >> 16);
}
__device__ __forceinline__ float bf2f(short h) {
    return __uint_as_float(((unsigned)(unsigned short)h) << 16);
}
__device__ __forceinline__ float sigm(float x)  { return 1.0f / (1.0f + __expf(-x)); }
__device__ __forceinline__ float tanh_(float x) { return 2.0f / (1.0f + __expf(-2.0f * x)) - 1.0f; }

// Unpack 16 bf16 units from 6 seq-tagged words: word w = [u(3w) u(3w+1) u(3w+2) seq]
__device__ __forceinline__ void unpack16(const u64 W[6], u64 q[4]) {
    unsigned short u[16];
#pragma unroll
    for (int w = 0; w < 6; ++w)
#pragma unroll
        for (int k = 0; k < 3; ++k) {
            int j = 3 * w + k;
            if (j < 16) u[j] = (unsigned short)(W[w] >> (16 * k));
        }
#pragma unroll
    for (int t = 0; t < 4; ++t)
        q[t] = (u64)u[4*t] | ((u64)u[4*t+1] << 16) | ((u64)u[4*t+2] << 32) | ((u64)u[4*t+3] << 48);
}

// 256 persistent workgroups = 16 batch-groups (grp, 16 rows) x 16 hidden-chunks.
// Exchange protocol (seq-tagged data-poll, pure agent scope — the only transport
// proven reliable here in rounds 0-4):
//   * Every published 8B word = [3 bf16 units | seq16], seq = s+1 (1..513; never
//     0x0000/0xAAAA harness-poison values). Single atomic store => the seq
//     certifies exactly its own 3 units. NO store-ordering needed anywhere: no
//     vmcnt-ack, no flags, no poison pass.
//   * Per row per buffer: 16 chunks x 6 words (48B, word 5 holds 1 unit).
//   * 2 regions (parity s&1). Recycle-safety: a block publishes step s+2 only
//     after its s+1 gather, which required every block's s+1 publish, which sits
//     after that block's step-s gather barrier => no writer can overwrite a
//     region a reader still polls (same argument class as round-1, which passed).
//   * Readers: thread (row em, chunk ej) polls its 6 words/buf until all seq
//     match, repolls per-buffer; poll budget 2^17 => any surprise is a finite
//     absmax failure, never a hang.
__global__ __launch_bounds__(256, 1) void lstm_fused(
    const float* __restrict__ x,
    const float* __restrict__ Wih0, const float* __restrict__ Whh0,
    const float* __restrict__ bih0, const float* __restrict__ bhh0,
    const float* __restrict__ Wih1, const float* __restrict__ Whh1,
    const float* __restrict__ bih1, const float* __restrict__ bhh1,
    const float* __restrict__ Wfc,  const float* __restrict__ bfc,
    float* __restrict__ out, char* __restrict__ ws)
{
    u64* h0buf = (u64*)ws;                    // [2][16][16][96] seq-tagged words
    u64* h1buf = h0buf + 2 * 16 * 16 * 96;    // [2][16][16][96]
    // total = 768 KiB (< proven 1 MiB ws capacity)

    const int blk   = blockIdx.x;
    const int grp   = ((blk & 7) << 1) | ((blk >> 3) & 1); // batch-group 0..15
    const int chunk = blk >> 4;                            // hidden-chunk 0..15
    const int tid   = threadIdx.x;
    const int lane  = tid & 63;
    const int wave  = tid >> 6;      // gate index: 0=i 1=f 2=g 3=o
    const int quad  = lane >> 4;
    const int nn    = lane & 15;     // W-row within 16-row tile

    __shared__ short A0[16][328];    // [m][ x(64) | h0(256) ] + pad
    __shared__ short A1[16][520];    // [m][ h0(256) | h1(256) ] + pad
    __shared__ float gbuf[2][4][16][16];
    __shared__ float red[16][16];
    __shared__ __align__(16) short hls[2][16][16];  // h staging for publish pack
    __shared__ float ldspad[5120];   // occupancy limiter: ~57 KB -> 1 wg/CU

    // zero A buffers (h0[-1] = 0, h1[-1] = 0 for the s==1 layer1 step)
    for (int i = tid; i < 16 * 328; i += 256) (&A0[0][0])[i] = 0;
    for (int i = tid; i < 16 * 520; i += 256) (&A1[0][0])[i] = 0;

    // ---- static weight fragments -> registers (B operand: W[n][k], n=lane&15, k=quad*8+j)
    const int wrow = wave * HDIM + chunk * 16 + nn;
    short8 w0f[10];   // layer0: kb 0..1 = Wih0 (K 0..63), kb 2..9 = Whh0 (K 64..319)
    short8 w1f[16];   // layer1: kb 0..7 = Wih1 (K 0..255), kb 8..15 = Whh1 (K 256..511)
#pragma unroll
    for (int kb = 0; kb < 10; ++kb)
#pragma unroll
        for (int j = 0; j < 8; ++j) {
            int k = kb * 32 + quad * 8 + j;
            float v = (k < 64) ? Wih0[wrow * IDIM + k] : Whh0[wrow * HDIM + (k - 64)];
            w0f[kb][j] = f2bf(v);
        }
#pragma unroll
    for (int kb = 0; kb < 16; ++kb)
#pragma unroll
        for (int j = 0; j < 8; ++j) {
            int k = kb * 32 + quad * 8 + j;
            float v = (k < 256) ? Wih1[wrow * HDIM + k] : Whh1[wrow * HDIM + (k - 256)];
            w1f[kb][j] = f2bf(v);
        }
    const float bias0 = bih0[wrow] + bhh0[wrow];
    const float bias1 = bih1[wrow] + bhh1[wrow];

    const int em = tid >> 4;   // elementwise batch row (0..15)
    const int ej = tid & 15;   // elementwise hidden unit within chunk / gather chunk
    float c0 = 0.0f, c1 = 0.0f;

    auto load_x = [&](int t) {
        const float4 v = *(const float4*)&x[((size_t)(grp * 16 + em) * TT + t) * IDIM + ej * 4];
        short4v sv;
        sv[0] = f2bf(v.x); sv[1] = f2bf(v.y); sv[2] = f2bf(v.z); sv[3] = f2bf(v.w);
        *(short4v*)&A0[em][ej * 4] = sv;
    };

    __syncthreads();
    load_x(0);
    __syncthreads();

    // super-step s: layer0 computes h0[s] (s<T); layer1 computes h1[s-1] (s>=1)
    for (int s = 0; s <= TT; ++s) {
        if (s < TT) {
            f32x4 accA = {0.f, 0.f, 0.f, 0.f}, accB = {0.f, 0.f, 0.f, 0.f};
#pragma unroll
            for (int kb = 0; kb < 10; kb += 2) {   // 2 chains: halve dep latency
                short8 a0v = *(const short8*)&A0[nn][kb * 32 + quad * 8];
                short8 a1v = *(const short8*)&A0[nn][(kb + 1) * 32 + quad * 8];
                accA = __builtin_amdgcn_mfma_f32_16x16x32_bf16(a0v, w0f[kb],     accA, 0, 0, 0);
                accB = __builtin_amdgcn_mfma_f32_16x16x32_bf16(a1v, w0f[kb + 1], accB, 0, 0, 0);
            }
            const f32x4 acc = accA + accB;
#pragma unroll
            for (int r = 0; r < 4; ++r)
                gbuf[0][wave][quad * 4 + r][nn] = acc[r] + bias0;
        }
        if (s >= 1) {
            f32x4 accA = {0.f, 0.f, 0.f, 0.f}, accB = {0.f, 0.f, 0.f, 0.f};
#pragma unroll
            for (int kb = 0; kb < 16; kb += 2) {
                short8 a0v = *(const short8*)&A1[nn][kb * 32 + quad * 8];
                short8 a1v = *(const short8*)&A1[nn][(kb + 1) * 32 + quad * 8];
                accA = __builtin_amdgcn_mfma_f32_16x16x32_bf16(a0v, w1f[kb],     accA, 0, 0, 0);
                accB = __builtin_amdgcn_mfma_f32_16x16x32_bf16(a1v, w1f[kb + 1], accB, 0, 0, 0);
            }
            const f32x4 acc = accA + accB;
#pragma unroll
            for (int r = 0; r < 4; ++r)
                gbuf[1][wave][quad * 4 + r][nn] = acc[r] + bias1;
        }
        __syncthreads();

        // elementwise LSTM cell updates -> stage h in LDS (bf16)
        if (s < TT) {
            float gi = sigm (gbuf[0][0][em][ej]);
            float gf = sigm (gbuf[0][1][em][ej]);
            float gg = tanh_(gbuf[0][2][em][ej]);
            float go = sigm (gbuf[0][3][em][ej]);
            c0 = gf * c0 + gi * gg;
            hls[0][em][ej] = f2bf(go * tanh_(c0));
        }
        if (s >= 1) {
            float gi = sigm (gbuf[1][0][em][ej]);
            float gf = sigm (gbuf[1][1][em][ej]);
            float gg = tanh_(gbuf[1][2][em][ej]);
            float go = sigm (gbuf[1][3][em][ej]);
            c1 = gf * c1 + gi * gg;
            hls[1][em][ej] = f2bf(go * tanh_(c1));
        } else {
            hls[1][em][ej] = 0;
        }
        __syncthreads();   // hls complete

        // publish own chunk, seq-tagged: 96 lanes x (row r, word w), both buffers.
        // Fire-and-forget: no vmcnt, no flag — the seq in each word IS the flag.
        if (tid < 96) {
            const int r = tid / 6, w = tid % 6;
            const int j0 = 3 * w;
            const u64 sq = (u64)(unsigned)(s + 1) << 48;
            u64 v0 = (u64)(unsigned short)hls[0][r][j0];
            u64 v1 = (u64)(unsigned short)hls[1][r][j0];
            if (j0 + 1 < 16) {
                v0 |= (u64)(unsigned short)hls[0][r][j0 + 1] << 16;
                v1 |= (u64)(unsigned short)hls[1][r][j0 + 1] << 16;
            }
            if (j0 + 2 < 16) {
                v0 |= (u64)(unsigned short)hls[0][r][j0 + 2] << 32;
                v1 |= (u64)(unsigned short)hls[1][r][j0 + 2] << 32;
            }
            v0 |= sq; v1 |= sq;
            const size_t base = (((size_t)(s & 1) * 16 + grp) * 16 + r) * 96 + chunk * 6 + w;
            __hip_atomic_store(&h0buf[base], v0, __ATOMIC_RELAXED, __HIP_MEMORY_SCOPE_AGENT);
            __hip_atomic_store(&h1buf[base], v1, __ATOMIC_RELAXED, __HIP_MEMORY_SCOPE_AGENT);
        }

        if (s + 1 < TT) load_x(s + 1);   // overlap x prefetch with the poll

        // ---- seq-poll + gather: thread (em,ej) owns chunk ej of row em (6 words/buf)
        {
            const bool g0 = (s < TT), g1 = (s >= 1);
            const unsigned sq = (unsigned)(s + 1);
            const size_t rb = (((size_t)(s & 1) * 16 + grp) * 16 + em) * 96 + ej * 6;
            u64 W0[6], W1[6];
            bool ok0 = !g0, ok1 = !g1;
            int budget = 1 << 17;   // hang-proofing: exhaust -> finite absmax diagnostic
            while ((!ok0 || !ok1) && budget-- > 0) {
                if (!ok0) {
#pragma unroll
                    for (int i = 0; i < 6; ++i)
                        W0[i] = __hip_atomic_load(&h0buf[rb + i],
                                                  __ATOMIC_RELAXED, __HIP_MEMORY_SCOPE_AGENT);
                    bool t = true;
#pragma unroll
                    for (int i = 0; i < 6; ++i) t &= ((unsigned)(W0[i] >> 48) == sq);
                    ok0 = t;
                }
                if (!ok1) {
#pragma unroll
                    for (int i = 0; i < 6; ++i)
                        W1[i] = __hip_atomic_load(&h1buf[rb + i],
                                                  __ATOMIC_RELAXED, __HIP_MEMORY_SCOPE_AGENT);
                    bool t = true;
#pragma unroll
                    for (int i = 0; i < 6; ++i) t &= ((unsigned)(W1[i] >> 48) == sq);
                    ok1 = t;
                }
            }
            // drain (also guarantees our earlier same-address publishes retired in order
            // before next iteration's publish to the other region)
            asm volatile("s_waitcnt vmcnt(0)" ::: "memory");

            if (g0) {
                u64 q[4]; unpack16(W0, q);
                u64* d0 = (u64*)&A0[em][64 + ej * 16];
                u64* d1 = (u64*)&A1[em][ej * 16];
#pragma unroll
                for (int t = 0; t < 4; ++t) { d0[t] = q[t]; d1[t] = q[t]; }
            }
            if (g1) {
                u64 q[4]; unpack16(W1, q);
                u64* d2 = (u64*)&A1[em][256 + ej * 16];
#pragma unroll
                for (int t = 0; t < 4; ++t) d2[t] = q[t];
            }
        }
        __syncthreads();
    }

    // FC epilogue: A1[:,256..511] holds h1[T-1] (bf16)
    {
        float part = 0.f;
#pragma unroll
        for (int kk = 0; kk < 16; ++kk) {
            int k = ej * 16 + kk;
            part += bf2f(A1[em][256 + k]) * Wfc[k];
        }
        red[em][ej] = part;
    }
    __syncthreads();
    if (chunk == 0 && tid < 16) {
        float sum = bfc[0];
#pragma unroll
        for (int c = 0; c < 16; ++c) sum += red[tid][c];
        out[grp * 16 + tid] = sum;
    }

    // keep ldspad allocated (occupancy cap); never true at runtime
    if (gridDim.x > 100000) { ldspad[tid] = bias0; out[0] = ldspad[255 - tid]; }
}

extern "C" void kernel_launch(void* const* d_in, const int* in_sizes, int n_in,
                              void* d_out, int out_size, void* d_ws, size_t ws_size,
                              hipStream_t stream) {
    (void)in_sizes; (void)n_in; (void)out_size; (void)ws_size;
    const float* x    = (const float*)d_in[0];
    const float* Wih0 = (const float*)d_in[1];
    const float* Whh0 = (const float*)d_in[2];
    const float* bih0 = (const float*)d_in[3];
    const float* bhh0 = (const float*)d_in[4];
    const float* Wih1 = (const float*)d_in[5];
    const float* Whh1 = (const float*)d_in[6];
    const float* bih1 = (const float*)d_in[7];
    const float* bhh1 = (const float*)d_in[8];
    const float* Wfc  = (const float*)d_in[9];
    const float* bfc  = (const float*)d_in[10];

    lstm_fused<<<256, 256, 0, stream>>>(x, Wih0, Whh0, bih0, bhh0,
                                        Wih1, Whh1, bih1, bhh1, Wfc, bfc,
                                        (float*)d_out, (char*)d_ws);
}

// Round 6
// 1788.674 us; speedup vs baseline: 1.4707x; 1.0121x over previous
//
#include <hip/hip_runtime.h>

#define TT   512
#define IDIM 64
#define HDIM 256

typedef short  short8  __attribute__((ext_vector_type(8)));
typedef short  short4v __attribute__((ext_vector_type(4)));
typedef float  f32x4   __attribute__((ext_vector_type(4)));
typedef unsigned long long u64;

__device__ __forceinline__ short f2bf(float f) {
    unsigned u = __float_as_uint(f);
    u = u + 0x7FFFu + ((u >> 16) & 1u);   // round-to-nearest-even
    return (short)(u >> 16);
}
__device__ __forceinline__ float bf2f(short h) {
    return __uint_as_float(((unsigned)(unsigned short)h) << 16);
}
__device__ __forceinline__ float sigm(float x)  { return 1.0f / (1.0f + __expf(-x)); }
__device__ __forceinline__ float tanh_(float x) { return 2.0f / (1.0f + __expf(-2.0f * x)) - 1.0f; }

// Unpack 16 bf16 units from 6 seq-tagged words: word w = [u(3w) u(3w+1) u(3w+2) seq]
__device__ __forceinline__ void unpack16(const u64 W[6], u64 q[4]) {
    unsigned short u[16];
#pragma unroll
    for (int w = 0; w < 6; ++w)
#pragma unroll
        for (int k = 0; k < 3; ++k) {
            int j = 3 * w + k;
            if (j < 16) u[j] = (unsigned short)(W[w] >> (16 * k));
        }
#pragma unroll
    for (int t = 0; t < 4; ++t)
        q[t] = (u64)u[4*t] | ((u64)u[4*t+1] << 16) | ((u64)u[4*t+2] << 32) | ((u64)u[4*t+3] << 48);
}

// 256 persistent workgroups = 16 batch-groups (grp, 16 rows) x 16 hidden-chunks.
// Exchange: seq-tagged data-poll (round-5-PROVEN), with ONE transport change:
// publishes are agent-scope atomic SWAPS (result discarded -> non-returning
// global_atomic_swap_x2). Rationale: rounds 0 and 5 tie at ~3.5us/step despite
// different round-trip counts; WRITE_SIZE == publish volume shows sc1 plain
// stores drain to HBM as lazy writebacks — that writeback IS the remote-
// visibility delay. Atomic RMWs execute AT the coherence point (memory-side),
// eliminating the dirty-line linger. Readers unchanged (relaxed agent loads,
// proven to observe). Seq word = [3 bf16 | seq16], seq = s+1: the tag certifies
// its own 3 units; no flags, no acks, no poison, no ordering requirements.
// 2 regions (parity); recycle-safety as round 5 (publish s+2 only after s+1
// gather => no overwrite of a polled region). Poll budget => hang-proof.
__global__ __launch_bounds__(256, 1) void lstm_fused(
    const float* __restrict__ x,
    const float* __restrict__ Wih0, const float* __restrict__ Whh0,
    const float* __restrict__ bih0, const float* __restrict__ bhh0,
    const float* __restrict__ Wih1, const float* __restrict__ Whh1,
    const float* __restrict__ bih1, const float* __restrict__ bhh1,
    const float* __restrict__ Wfc,  const float* __restrict__ bfc,
    float* __restrict__ out, char* __restrict__ ws)
{
    u64* h0buf = (u64*)ws;                    // [2][16][16][96] seq-tagged words
    u64* h1buf = h0buf + 2 * 16 * 16 * 96;    // [2][16][16][96]
    // total = 768 KiB (< proven 1 MiB ws capacity)

    const int blk   = blockIdx.x;
    const int grp   = ((blk & 7) << 1) | ((blk >> 3) & 1); // batch-group 0..15
    const int chunk = blk >> 4;                            // hidden-chunk 0..15
    const int tid   = threadIdx.x;
    const int lane  = tid & 63;
    const int wave  = tid >> 6;      // gate index: 0=i 1=f 2=g 3=o
    const int quad  = lane >> 4;
    const int nn    = lane & 15;     // W-row within 16-row tile

    __shared__ short A0[16][328];    // [m][ x(64) | h0(256) ] + pad
    __shared__ short A1[16][520];    // [m][ h0(256) | h1(256) ] + pad
    __shared__ float gbuf[2][4][16][17];  // row pad 16->17: de-alias 4-way bank
                                          // conflict (quads wrote same 16 banks)
    __shared__ float red[16][16];
    __shared__ __align__(16) short hls[2][16][16];  // h staging for publish pack
    __shared__ float ldspad[5120];   // occupancy limiter: ~57 KB -> 1 wg/CU

    // zero A buffers (h0[-1] = 0, h1[-1] = 0 for the s==1 layer1 step)
    for (int i = tid; i < 16 * 328; i += 256) (&A0[0][0])[i] = 0;
    for (int i = tid; i < 16 * 520; i += 256) (&A1[0][0])[i] = 0;

    // ---- static weight fragments -> registers (B operand: W[n][k], n=lane&15, k=quad*8+j)
    const int wrow = wave * HDIM + chunk * 16 + nn;
    short8 w0f[10];   // layer0: kb 0..1 = Wih0 (K 0..63), kb 2..9 = Whh0 (K 64..319)
    short8 w1f[16];   // layer1: kb 0..7 = Wih1 (K 0..255), kb 8..15 = Whh1 (K 256..511)
#pragma unroll
    for (int kb = 0; kb < 10; ++kb)
#pragma unroll
        for (int j = 0; j < 8; ++j) {
            int k = kb * 32 + quad * 8 + j;
            float v = (k < 64) ? Wih0[wrow * IDIM + k] : Whh0[wrow * HDIM + (k - 64)];
            w0f[kb][j] = f2bf(v);
        }
#pragma unroll
    for (int kb = 0; kb < 16; ++kb)
#pragma unroll
        for (int j = 0; j < 8; ++j) {
            int k = kb * 32 + quad * 8 + j;
            float v = (k < 256) ? Wih1[wrow * HDIM + k] : Whh1[wrow * HDIM + (k - 256)];
            w1f[kb][j] = f2bf(v);
        }
    const float bias0 = bih0[wrow] + bhh0[wrow];
    const float bias1 = bih1[wrow] + bhh1[wrow];

    const int em = tid >> 4;   // elementwise batch row (0..15)
    const int ej = tid & 15;   // elementwise hidden unit within chunk / gather chunk
    float c0 = 0.0f, c1 = 0.0f;

    auto load_x = [&](int t) {
        const float4 v = *(const float4*)&x[((size_t)(grp * 16 + em) * TT + t) * IDIM + ej * 4];
        short4v sv;
        sv[0] = f2bf(v.x); sv[1] = f2bf(v.y); sv[2] = f2bf(v.z); sv[3] = f2bf(v.w);
        *(short4v*)&A0[em][ej * 4] = sv;
    };

    __syncthreads();
    load_x(0);
    __syncthreads();

    // super-step s: layer0 computes h0[s] (s<T); layer1 computes h1[s-1] (s>=1)
    for (int s = 0; s <= TT; ++s) {
        if (s < TT) {
            f32x4 accA = {0.f, 0.f, 0.f, 0.f}, accB = {0.f, 0.f, 0.f, 0.f};
#pragma unroll
            for (int kb = 0; kb < 10; kb += 2) {   // 2 chains: halve dep latency
                short8 a0v = *(const short8*)&A0[nn][kb * 32 + quad * 8];
                short8 a1v = *(const short8*)&A0[nn][(kb + 1) * 32 + quad * 8];
                accA = __builtin_amdgcn_mfma_f32_16x16x32_bf16(a0v, w0f[kb],     accA, 0, 0, 0);
                accB = __builtin_amdgcn_mfma_f32_16x16x32_bf16(a1v, w0f[kb + 1], accB, 0, 0, 0);
            }
            const f32x4 acc = accA + accB;
#pragma unroll
            for (int r = 0; r < 4; ++r)
                gbuf[0][wave][quad * 4 + r][nn] = acc[r] + bias0;
        }
        if (s >= 1) {
            f32x4 accA = {0.f, 0.f, 0.f, 0.f}, accB = {0.f, 0.f, 0.f, 0.f};
#pragma unroll
            for (int kb = 0; kb < 16; kb += 2) {
                short8 a0v = *(const short8*)&A1[nn][kb * 32 + quad * 8];
                short8 a1v = *(const short8*)&A1[nn][(kb + 1) * 32 + quad * 8];
                accA = __builtin_amdgcn_mfma_f32_16x16x32_bf16(a0v, w1f[kb],     accA, 0, 0, 0);
                accB = __builtin_amdgcn_mfma_f32_16x16x32_bf16(a1v, w1f[kb + 1], accB, 0, 0, 0);
            }
            const f32x4 acc = accA + accB;
#pragma unroll
            for (int r = 0; r < 4; ++r)
                gbuf[1][wave][quad * 4 + r][nn] = acc[r] + bias1;
        }
        __syncthreads();

        // elementwise LSTM cell updates -> stage h in LDS (bf16)
        if (s < TT) {
            float gi = sigm (gbuf[0][0][em][ej]);
            float gf = sigm (gbuf[0][1][em][ej]);
            float gg = tanh_(gbuf[0][2][em][ej]);
            float go = sigm (gbuf[0][3][em][ej]);
            c0 = gf * c0 + gi * gg;
            hls[0][em][ej] = f2bf(go * tanh_(c0));
        }
        if (s >= 1) {
            float gi = sigm (gbuf[1][0][em][ej]);
            float gf = sigm (gbuf[1][1][em][ej]);
            float gg = tanh_(gbuf[1][2][em][ej]);
            float go = sigm (gbuf[1][3][em][ej]);
            c1 = gf * c1 + gi * gg;
            hls[1][em][ej] = f2bf(go * tanh_(c1));
        } else {
            hls[1][em][ej] = 0;
        }
        __syncthreads();   // hls complete

        // publish own chunk, seq-tagged, via agent-scope atomic SWAP (result
        // discarded -> non-returning swap executed AT the coherence point: no
        // dirty-line writeback delay). The seq in each word IS the flag.
        if (tid < 96) {
            const int r = tid / 6, w = tid % 6;
            const int j0 = 3 * w;
            const u64 sq = (u64)(unsigned)(s + 1) << 48;
            u64 v0 = (u64)(unsigned short)hls[0][r][j0];
            u64 v1 = (u64)(unsigned short)hls[1][r][j0];
            if (j0 + 1 < 16) {
                v0 |= (u64)(unsigned short)hls[0][r][j0 + 1] << 16;
                v1 |= (u64)(unsigned short)hls[1][r][j0 + 1] << 16;
            }
            if (j0 + 2 < 16) {
                v0 |= (u64)(unsigned short)hls[0][r][j0 + 2] << 32;
                v1 |= (u64)(unsigned short)hls[1][r][j0 + 2] << 32;
            }
            v0 |= sq; v1 |= sq;
            const size_t base = (((size_t)(s & 1) * 16 + grp) * 16 + r) * 96 + chunk * 6 + w;
            (void)__hip_atomic_exchange(&h0buf[base], v0,
                                        __ATOMIC_RELAXED, __HIP_MEMORY_SCOPE_AGENT);
            (void)__hip_atomic_exchange(&h1buf[base], v1,
                                        __ATOMIC_RELAXED, __HIP_MEMORY_SCOPE_AGENT);
        }

        if (s + 1 < TT) load_x(s + 1);   // overlap x prefetch with the poll

        // ---- seq-poll + gather: thread (em,ej) owns chunk ej of row em (6 words/buf)
        {
            const bool g0 = (s < TT), g1 = (s >= 1);
            const unsigned sq = (unsigned)(s + 1);
            const size_t rb = (((size_t)(s & 1) * 16 + grp) * 16 + em) * 96 + ej * 6;
            u64 W0[6], W1[6];
            bool ok0 = !g0, ok1 = !g1;
            int budget = 1 << 17;   // hang-proofing: exhaust -> finite absmax diagnostic
            while ((!ok0 || !ok1) && budget-- > 0) {
                if (!ok0) {
#pragma unroll
                    for (int i = 0; i < 6; ++i)
                        W0[i] = __hip_atomic_load(&h0buf[rb + i],
                                                  __ATOMIC_RELAXED, __HIP_MEMORY_SCOPE_AGENT);
                    bool t = true;
#pragma unroll
                    for (int i = 0; i < 6; ++i) t &= ((unsigned)(W0[i] >> 48) == sq);
                    ok0 = t;
                }
                if (!ok1) {
#pragma unroll
                    for (int i = 0; i < 6; ++i)
                        W1[i] = __hip_atomic_load(&h1buf[rb + i],
                                                  __ATOMIC_RELAXED, __HIP_MEMORY_SCOPE_AGENT);
                    bool t = true;
#pragma unroll
                    for (int i = 0; i < 6; ++i) t &= ((unsigned)(W1[i] >> 48) == sq);
                    ok1 = t;
                }
            }
            // drain: our publishes (and poll loads) retired before next region reuse
            asm volatile("s_waitcnt vmcnt(0)" ::: "memory");

            if (g0) {
                u64 q[4]; unpack16(W0, q);
                u64* d0 = (u64*)&A0[em][64 + ej * 16];
                u64* d1 = (u64*)&A1[em][ej * 16];
#pragma unroll
                for (int t = 0; t < 4; ++t) { d0[t] = q[t]; d1[t] = q[t]; }
            }
            if (g1) {
                u64 q[4]; unpack16(W1, q);
                u64* d2 = (u64*)&A1[em][256 + ej * 16];
#pragma unroll
                for (int t = 0; t < 4; ++t) d2[t] = q[t];
            }
        }
        __syncthreads();
    }

    // FC epilogue: A1[:,256..511] holds h1[T-1] (bf16)
    {
        float part = 0.f;
#pragma unroll
        for (int kk = 0; kk < 16; ++kk) {
            int k = ej * 16 + kk;
            part += bf2f(A1[em][256 + k]) * Wfc[k];
        }
        red[em][ej] = part;
    }
    __syncthreads();
    if (chunk == 0 && tid < 16) {
        float sum = bfc[0];
#pragma unroll
        for (int c = 0; c < 16; ++c) sum += red[tid][c];
        out[grp * 16 + tid] = sum;
    }

    // keep ldspad allocated (occupancy cap); never true at runtime
    if (gridDim.x > 100000) { ldspad[tid] = bias0; out[0] = ldspad[255 - tid]; }
}

extern "C" void kernel_launch(void* const* d_in, const int* in_sizes, int n_in,
                              void* d_out, int out_size, void* d_ws, size_t ws_size,
                              hipStream_t stream) {
    (void)in_sizes; (void)n_in; (void)out_size; (void)ws_size;
    const float* x    = (const float*)d_in[0];
    const float* Wih0 = (const float*)d_in[1];
    const float* Whh0 = (const float*)d_in[2];
    const float* bih0 = (const float*)d_in[3];
    const float* bhh0 = (const float*)d_in[4];
    const float* Wih1 = (const float*)d_in[5];
    const float* Whh1 = (const float*)d_in[6];
    const float* bih1 = (const float*)d_in[7];
    const float* bhh1 = (const float*)d_in[8];
    const float* Wfc  = (const float*)d_in[9];
    const float* bfc  = (const float*)d_in[10];

    lstm_fused<<<256, 256, 0, stream>>>(x, Wih0, Whh0, bih0, bhh0,
                                        Wih1, Whh1, bih1, bhh1, Wfc, bfc,
                                        (float*)d_out, (char*)d_ws);
}